// Round 15
// baseline (118.942 us; speedup 1.0000x reference)
//
#include <hip/hip_runtime.h>
#include <hip/hip_fp16.h>

typedef _Float16 f16;
typedef __attribute__((ext_vector_type(8))) _Float16 half8;
typedef __attribute__((ext_vector_type(2))) __fp16 fp16x2_native;
typedef __attribute__((ext_vector_type(4))) float floatx4;
typedef __attribute__((ext_vector_type(16))) float f32x16;
typedef __attribute__((ext_vector_type(4))) unsigned uint4v;
typedef __attribute__((ext_vector_type(2))) unsigned uint2v;

static constexpr int DIM = 1024;
static constexpr int SEQ = 2048;
static constexpr int DH = 64;
static constexpr int MTOT = 4096;  // BATCH * SEQ

__device__ __forceinline__ float fexp2(float x) {
#if __has_builtin(__builtin_amdgcn_exp2f)
  return __builtin_amdgcn_exp2f(x);
#else
  return exp2f(x);
#endif
}

__device__ __forceinline__ unsigned pkrtz(float a, float b) {
  fp16x2_native h = __builtin_amdgcn_cvt_pkrtz(a, b);
  return __builtin_bit_cast(unsigned, h);
}

__device__ __forceinline__ void pl32swap(unsigned& a, unsigned& b) {
#if __has_builtin(__builtin_amdgcn_permlane32_swap)
  uint2v r = __builtin_amdgcn_permlane32_swap(a, b, false, false);
  a = r.x;
  b = r.y;
#else
  asm volatile("v_permlane32_swap_b32 %0, %1" : "+v"(a), "+v"(b));
#endif
}

// async global->LDS 16B
__device__ __forceinline__ void gll16(const f16* g, f16* l) {
  auto gp = (__attribute__((address_space(1))) unsigned*)(uintptr_t)(const void*)g;
  auto lp = (__attribute__((address_space(3))) unsigned*)(uintptr_t)(void*)l;
  __builtin_amdgcn_global_load_lds(gp, lp, 16, 0, 0);
}

// ---- prep: z<4 = weight transpose+fp16 (wt[z][n][k]=W_z[k][n]); z==4 = x fp32->fp16 ----
__global__ __launch_bounds__(256) void k_prep(
    const float* __restrict__ Wq, const float* __restrict__ Wk,
    const float* __restrict__ Wv, const float* __restrict__ Wo,
    const float* __restrict__ x, f16* __restrict__ wt, f16* __restrict__ xh)
{
  const int z = blockIdx.z;
  const int tx = threadIdx.x, ty = threadIdx.y;
  if (z == 4) {
    const int i = (blockIdx.y * 32 + blockIdx.x) * 256 + ty * 32 + tx;  // 0..262143
    const float4* p = (const float4*)x + (size_t)i * 4;
    float4 v0 = p[0], v1 = p[1], v2 = p[2], v3 = p[3];
    half8 h0 = {(f16)v0.x, (f16)v0.y, (f16)v0.z, (f16)v0.w,
                (f16)v1.x, (f16)v1.y, (f16)v1.z, (f16)v1.w};
    half8 h1 = {(f16)v2.x, (f16)v2.y, (f16)v2.z, (f16)v2.w,
                (f16)v3.x, (f16)v3.y, (f16)v3.z, (f16)v3.w};
    *(half8*)(xh + (size_t)i * 16) = h0;
    *(half8*)(xh + (size_t)i * 16 + 8) = h1;
    return;
  }
  __shared__ float tile[32][33];
  const float* W = (z == 0) ? Wq : (z == 1) ? Wk : (z == 2) ? Wv : Wo;
  f16* out = wt + (size_t)z * DIM * DIM;
  const int x0 = blockIdx.x * 32, y0 = blockIdx.y * 32;
#pragma unroll
  for (int i = 0; i < 4; ++i)
    tile[ty + i * 8][tx] = W[(size_t)(y0 + ty + i * 8) * DIM + (x0 + tx)];
  __syncthreads();
#pragma unroll
  for (int i = 0; i < 4; ++i)
    out[(size_t)(x0 + ty + i * 8) * DIM + (y0 + tx)] = (f16)tile[tx][ty + i * 8];
}

// ---- V^T pre-transpose: vt[bh][d][n] = V[b][n][h*64+d] ----
__global__ __launch_bounds__(256) void k_vtrans(
    const f16* __restrict__ vh, f16* __restrict__ vt)
{
  __shared__ f16 T[64][72];
  const int tid = threadIdx.x;
  const int nt = blockIdx.x, bh = blockIdx.y;
  const int b = bh >> 4, h = bh & 15;
  const int n0 = nt * 64;
  const f16* src = vh + (size_t)b * SEQ * DIM + (size_t)h * DH;
#pragma unroll
  for (int i = 0; i < 2; ++i) {
    const int n = (tid >> 3) + i * 32;
    const int cc = tid & 7;
    half8 v = *(const half8*)(src + (size_t)(n0 + n) * DIM + cc * 8);
#pragma unroll
    for (int j = 0; j < 8; ++j) T[cc * 8 + j][n] = v[j];
  }
  __syncthreads();
  f16* dst = vt + (size_t)bh * DH * SEQ;
#pragma unroll
  for (int i = 0; i < 2; ++i) {
    const int d = (tid >> 3) + i * 32;
    const int cc = tid & 7;
    half8 w = *(const half8*)&T[d][cc * 8];
    *(half8*)(dst + (size_t)d * SEQ + n0 + cc * 8) = w;
  }
}

// ---- QKV GEMM v5: 128x128 tile, BK=32, 3 LDS buffers (48KB -> 3 blocks/CU),
//      depth-2 prefetch, counted vmcnt(4), compile-time buffer indices ----
// A: xh [4096][1024]; BT: wt [3072][1024]; C: qkvh [3][4096][1024]
__global__ __launch_bounds__(256) void k_gemm5(
    const f16* __restrict__ A, const f16* __restrict__ BT, f16* __restrict__ C)
{
  __shared__ f16 SB[3][8192];  // per buf: A [128][32] at 0, B [128][32] at 4096

  const int tid = threadIdx.x;
  const int lane = tid & 63;
  const int wid = tid >> 6;
  const int wr = (wid >> 1) * 64, wc = (wid & 1) * 64;
  const int li = lane & 15, lg = lane >> 4;

  // XCD-chunked swizzle: 768 blocks, 96/XCD = 3 full B-panels per XCD
  const int id = blockIdx.x;
  const int wg = (id & 7) * 96 + (id >> 3);
  const int bx = wg & 31;
  const int by = wg >> 5;       // 0..23
  const int row0 = bx * 128;
  const int col0 = by * 128;

  // staging: A 512 chunks + B 512 chunks of 16B; 2+2 per thread.
  // phys chunk (row, p) holds source col-chunk p ^ ((row>>1)&3)
  const int c0 = tid, c1 = tid + 256;
  const int r0 = c0 >> 2, sw0 = (((c0 & 3) ^ ((c0 >> 3) & 3))) * 8;
  const int r1 = c1 >> 2, sw1 = (((c1 & 3) ^ ((c1 >> 3) & 3))) * 8;
  const f16* pa0 = A + (size_t)(row0 + r0) * DIM + sw0;
  const f16* pa1 = A + (size_t)(row0 + r1) * DIM + sw1;
  const f16* pb0 = BT + (size_t)(col0 + r0) * DIM + sw0;
  const f16* pb1 = BT + (size_t)(col0 + r1) * DIM + sw1;
  const int da0 = wid * 512, da1 = 2048 + wid * 512;

  auto issue = [&](int d) {
    gll16(pa0, &SB[d][da0]);
    gll16(pa1, &SB[d][da1]);
    gll16(pb0, &SB[d][4096 + da0]);
    gll16(pb1, &SB[d][4096 + da1]);
    pa0 += 32; pa1 += 32; pb0 += 32; pb1 += 32;
  };

  const floatx4 zero4 = {0.f, 0.f, 0.f, 0.f};
  floatx4 acc[4][4];
#pragma unroll
  for (int m = 0; m < 4; ++m)
#pragma unroll
    for (int n = 0; n < 4; ++n) acc[m][n] = zero4;

  issue(0);
  issue(1);

  auto step = [&](int d, int t) {
    if (t < 31)
      asm volatile("s_waitcnt vmcnt(4)" ::: "memory");  // tile t complete; t+1 in flight
    else
      asm volatile("s_waitcnt vmcnt(0)" ::: "memory");
    __builtin_amdgcn_s_barrier();
    if (t + 2 < 32) {
      const int nb = (d + 2 >= 3) ? d - 1 : d + 2;  // compile-time at call sites
      issue(nb);
    }
    const f16* As = &SB[d][0];
    const f16* Bs = &SB[d][4096];
    half8 af[4], bf[4];
#pragma unroll
    for (int m = 0; m < 4; ++m) {
      const int ra = wr + m * 16 + li;
      af[m] = *(const half8*)&As[ra * 32 + (lg ^ ((ra >> 1) & 3)) * 8];
    }
#pragma unroll
    for (int n = 0; n < 4; ++n) {
      const int rb = wc + n * 16 + li;
      bf[n] = *(const half8*)&Bs[rb * 32 + (lg ^ ((rb >> 1) & 3)) * 8];
    }
    __builtin_amdgcn_s_setprio(1);
#pragma unroll
    for (int m = 0; m < 4; ++m)
#pragma unroll
      for (int n = 0; n < 4; ++n)
        acc[m][n] = __builtin_amdgcn_mfma_f32_16x16x32_f16(af[m], bf[n], acc[m][n], 0, 0, 0);
    __builtin_amdgcn_s_setprio(0);
  };

  for (int tt = 0; tt < 30; tt += 3) {
    step(0, tt);
    step(1, tt + 1);
    step(2, tt + 2);
  }
  step(0, 30);
  step(1, 31);

#pragma unroll
  for (int m = 0; m < 4; ++m)
#pragma unroll
    for (int n = 0; n < 4; ++n) {
      const int colg = col0 + wc + n * 16 + li;
      f16* Cz = C + (size_t)(colg >> 10) * ((size_t)MTOT * DIM) + (colg & 1023);
#pragma unroll
      for (int r = 0; r < 4; ++r) {
        const int row = row0 + wr + m * 16 + lg * 4 + r;
        Cz[(size_t)row * DIM] = (f16)acc[m][n][r];
      }
    }
}

// ---- out-proj GEMM: 128x64 tile, 2-buffer, vmcnt(0) (r11 proven) ----
__global__ __launch_bounds__(256) void k_gemm3(
    const f16* __restrict__ A, const f16* __restrict__ BT,
    float* __restrict__ C, const float* __restrict__ bias)
{
  __shared__ f16 SB[2][6144];  // A 4096 f16 | B 2048 f16

  const int tid = threadIdx.x;
  const int lane = tid & 63;
  const int wid = tid >> 6;
  const int wr = (wid >> 1) * 64, wc = (wid & 1) * 32;
  const int li = lane & 15, lg = lane >> 4;

  const int row0 = blockIdx.x * 128, col0 = blockIdx.y * 64;

  const int c0 = tid, c1 = tid + 256;
  const f16* a0 = A + (size_t)(row0 + (c0 >> 2)) * DIM + (c0 & 3) * 8;
  const f16* a1 = A + (size_t)(row0 + (c1 >> 2)) * DIM + (c1 & 3) * 8;
  const f16* b0 = BT + (size_t)(col0 + (tid >> 2)) * DIM + (tid & 3) * 8;

  const floatx4 zero4 = {0.f, 0.f, 0.f, 0.f};
  floatx4 acc[4][2];
#pragma unroll
  for (int m = 0; m < 4; ++m)
#pragma unroll
    for (int n = 0; n < 2; ++n) acc[m][n] = zero4;

  auto issue = [&](int buf) {
    f16* B = &SB[buf][0];
    gll16(a0, B + tid * 8);
    gll16(a1, B + 2048 + tid * 8);
    gll16(b0, B + 4096 + tid * 8);
    a0 += 32; a1 += 32; b0 += 32;
  };

  issue(0);

  auto step = [&](int buf, int t) {
    asm volatile("s_waitcnt vmcnt(0)" ::: "memory");
    __builtin_amdgcn_s_barrier();
    asm volatile("" ::: "memory");
    if (t + 1 < 32) issue(buf ^ 1);
    const f16* As = &SB[buf][0];
    const f16* Bs = &SB[buf][4096];
    half8 af[4], bf[2];
#pragma unroll
    for (int m = 0; m < 4; ++m)
      af[m] = *(const half8*)&As[(wr + m * 16 + li) * 32 + lg * 8];
#pragma unroll
    for (int n = 0; n < 2; ++n)
      bf[n] = *(const half8*)&Bs[(wc + n * 16 + li) * 32 + lg * 8];
#pragma unroll
    for (int m = 0; m < 4; ++m)
#pragma unroll
      for (int n = 0; n < 2; ++n)
        acc[m][n] = __builtin_amdgcn_mfma_f32_16x16x32_f16(af[m], bf[n], acc[m][n], 0, 0, 0);
  };

  for (int t2 = 0; t2 < 32; t2 += 2) {
    step(0, t2);
    step(1, t2 + 1);
  }

#pragma unroll
  for (int m = 0; m < 4; ++m)
#pragma unroll
    for (int n = 0; n < 2; ++n)
#pragma unroll
      for (int r = 0; r < 4; ++r) {
        const int row = row0 + wr + m * 16 + lg * 4 + r;
        const int col = col0 + wc + n * 16 + li;
        C[(size_t)row * DIM + col] = acc[m][n][r] + bias[col];
      }
}

// ---- flash attention v9 (r14 proven, unchanged) ----
__global__ __launch_bounds__(512) void k_attn9(
    const f16* __restrict__ qh, const f16* __restrict__ kh,
    const f16* __restrict__ vt, f16* __restrict__ oh)
{
  __shared__ f16 KV[2][16384];   // [buf][K0|V0|K1|V1] 4096 f16 each, 16B-col swizzled
  __shared__ float bc[8][32];
  __shared__ float Lm[4][32], Ll[4][32], W0[4][32], W1[4][32];

  const int tid = threadIdx.x;
  const int lane = tid & 63;
  const int wid = tid >> 6;   // 0..7
  const int g = wid >> 2;     // kv-half group
  const int sub = wid & 3;    // q-subtile
  const int col = lane & 31;
  const int hi = lane >> 5;

  const int id = blockIdx.x;
  const int xcd = id & 7;
  const int j = id >> 3;
  const int bh = xcd * 4 + (j >> 4);
  const int qi = j & 15;
  const int b = bh >> 4, h = bh & 15;

  const int q0 = qi * 128 + sub * 32;
  const size_t xbase = (size_t)b * SEQ * DIM + (size_t)h * DH;
  const size_t vtbase = (size_t)bh * DH * SEQ;

  const float SC = 0.125f * 1.44269504089f;  // scale * log2(e)
  const float RTRAW = 8.0f / SC;

  const int lc = tid & 511;
  const int srow = lc >> 3;
  const int sw = ((lc & 7) ^ (srow & 7)) * 8;
  const f16* ks0 = kh + xbase + (size_t)srow * DIM + sw;
  const f16* ks1 = kh + xbase + (size_t)(1024 + srow) * DIM + sw;
  const f16* vs0 = vt + vtbase + (size_t)srow * SEQ + sw;
  const f16* vs1 = vt + vtbase + (size_t)srow * SEQ + 1024 + sw;

  auto issue = [&](int buf) {
    f16* B = &KV[buf][wid * 512];
    gll16(ks0, B);
    gll16(vs0, B + 4096);
    gll16(ks1, B + 8192);
    gll16(vs1, B + 12288);
    ks0 += 64 * DIM; ks1 += 64 * DIM; vs0 += 64; vs1 += 64;
  };

  half8 qb[4];
  {
    const f16* qrow = qh + xbase + (size_t)(q0 + col) * DIM;
#pragma unroll
    for (int s = 0; s < 4; ++s) qb[s] = *(const half8*)(qrow + s * 16 + hi * 8);
  }

  f32x16 o0 = {0, 0, 0, 0, 0, 0, 0, 0, 0, 0, 0, 0, 0, 0, 0, 0};
  f32x16 o1 = {0, 0, 0, 0, 0, 0, 0, 0, 0, 0, 0, 0, 0, 0, 0, 0};
  float m = -1e30f, mc = -1e30f;  // mc = m*SC kept in sync
  float lsum = 0.f;               // per-lane half-row partial

  issue(0);

  auto tile = [&](int buf, int t) {
    asm volatile("s_waitcnt vmcnt(0)" ::: "memory");
    __builtin_amdgcn_s_barrier();
    asm volatile("" ::: "memory");
    if (t < 15) issue(buf ^ 1);
    const f16* Ks = &KV[buf][g * 8192];
    const f16* Vs = Ks + 4096;

#pragma unroll
    for (int kvs = 0; kvs < 2; ++kvs) {
      const int krow = kvs * 32 + col;
      f32x16 sacc = {0, 0, 0, 0, 0, 0, 0, 0, 0, 0, 0, 0, 0, 0, 0, 0};
      __builtin_amdgcn_s_setprio(1);
#pragma unroll
      for (int s = 0; s < 4; ++s) {
        const int cc = (2 * s + hi) ^ (krow & 7);
        half8 ka = *(const half8*)&Ks[krow * 64 + cc * 8];
        sacc = __builtin_amdgcn_mfma_f32_32x32x16_f16(ka, qb[s], sacc, 0, 0, 0);
      }
      __builtin_amdgcn_s_setprio(0);

      // speculative exp2 with current m (off the max-tree path)
      float pw[16];
#pragma unroll
      for (int r = 0; r < 16; ++r) pw[r] = fexp2(fmaf(sacc[r], SC, -mc));

      float x0 = fmaxf(fmaxf(sacc[0], sacc[1]), fmaxf(sacc[2], sacc[3]));
      float x1 = fmaxf(fmaxf(sacc[4], sacc[5]), fmaxf(sacc[6], sacc[7]));
      float x2 = fmaxf(fmaxf(sacc[8], sacc[9]), fmaxf(sacc[10], sacc[11]));
      float x3 = fmaxf(fmaxf(sacc[12], sacc[13]), fmaxf(sacc[14], sacc[15]));
      const float smax = fmaxf(fmaxf(x0, x1), fmaxf(x2, x3));

      if (!__all(smax <= m + RTRAW)) {  // rare: first tile + outliers
        const float psm = fmaxf(smax, __shfl_xor(smax, 32));  // pair-consistent
        const float mn = fmaxf(m, psm);
        const float alpha = fexp2((m - mn) * SC);
        m = mn;
        mc = m * SC;
        lsum *= alpha;
        if (hi == 0) bc[wid][col] = alpha;
#pragma unroll
        for (int r = 0; r < 16; ++r) {
          const float a2 = bc[wid][(r & 3) + 8 * (r >> 2) + 4 * hi];
          o0[r] *= a2;
          o1[r] *= a2;
        }
#pragma unroll
        for (int r = 0; r < 16; ++r) pw[r] = fexp2(fmaf(sacc[r], SC, -mc));
      }

      float s0 = (pw[0] + pw[1]) + (pw[2] + pw[3]);
      float s1 = (pw[4] + pw[5]) + (pw[6] + pw[7]);
      float s2 = (pw[8] + pw[9]) + (pw[10] + pw[11]);
      float s3 = (pw[12] + pw[13]) + (pw[14] + pw[15]);
      lsum += (s0 + s1) + (s2 + s3);  // deferred combine

      __builtin_amdgcn_s_setprio(1);
#pragma unroll
      for (int s2i = 0; s2i < 2; ++s2i) {
        const int rb = s2i * 8;
        unsigned X0 = pkrtz(pw[rb + 0], pw[rb + 1]);
        unsigned X1 = pkrtz(pw[rb + 2], pw[rb + 3]);
        unsigned Y0 = pkrtz(pw[rb + 4], pw[rb + 5]);
        unsigned Y1 = pkrtz(pw[rb + 6], pw[rb + 7]);
        pl32swap(X0, Y0);
        pl32swap(X1, Y1);
        const half8 paf = __builtin_bit_cast(half8, (uint4v){X0, X1, Y0, Y1});
        const int kc = kvs * 4 + s2i * 2 + hi;
#pragma unroll
        for (int dt = 0; dt < 2; ++dt) {
          const int vrow = dt * 32 + col;
          const int cc = kc ^ (vrow & 7);
          half8 vb = *(const half8*)&Vs[vrow * 64 + cc * 8];
          if (dt == 0)
            o0 = __builtin_amdgcn_mfma_f32_32x32x16_f16(paf, vb, o0, 0, 0, 0);
          else
            o1 = __builtin_amdgcn_mfma_f32_32x32x16_f16(paf, vb, o1, 0, 0, 0);
        }
      }
      __builtin_amdgcn_s_setprio(0);
    }
  };

  for (int t2 = 0; t2 < 16; t2 += 2) {
    tile(0, t2);
    tile(1, t2 + 1);
  }

  lsum += __shfl_xor(lsum, 32);  // full row-sum for q = col

  if (g == 1) {
    const float inv = 1.0f / lsum;
    if (hi == 0) { Lm[sub][col] = m; Ll[sub][col] = lsum; bc[wid][col] = inv; }
    f16* po = &KV[0][0] + sub * 2048;
#pragma unroll
    for (int r = 0; r < 16; ++r) {
      const int qr = (r & 3) + 8 * (r >> 2) + 4 * hi;
      const float iv = bc[wid][qr];
      po[qr * 64 + col] = (f16)(o0[r] * iv);
      po[qr * 64 + 32 + col] = (f16)(o1[r] * iv);
    }
  }
  __syncthreads();
  if (g == 0) {
    const float m1 = Lm[sub][col], l1 = Ll[sub][col];
    const float M = fmaxf(m, m1);
    const float e0 = fexp2((m - M) * SC);
    const float a0 = lsum * e0;
    const float a1 = l1 * fexp2((m1 - M) * SC);
    const float rden = 1.0f / (a0 + a1);
    const float c0 = e0 * rden;
    const float w1 = a1 * rden;
    if (hi == 0) { W0[sub][col] = c0; W1[sub][col] = w1; }
    const f16* po = &KV[0][0] + sub * 2048;
#pragma unroll
    for (int r = 0; r < 16; ++r) {
      const int qr = (r & 3) + 8 * (r >> 2) + 4 * hi;
      const float c0r = W0[sub][qr], w1r = W1[sub][qr];
      f16* orow = oh + xbase + (size_t)(q0 + qr) * DIM;
      orow[col] = (f16)(c0r * o0[r] + w1r * (float)po[qr * 64 + col]);
      orow[32 + col] = (f16)(c0r * o1[r] + w1r * (float)po[qr * 64 + 32 + col]);
    }
  }
}

extern "C" void kernel_launch(void* const* d_in, const int* in_sizes, int n_in,
                              void* d_out, int out_size, void* d_ws, size_t ws_size,
                              hipStream_t stream)
{
  const float* x  = (const float*)d_in[0];
  const float* Wq = (const float*)d_in[1];
  const float* Wk = (const float*)d_in[2];
  const float* Wv = (const float*)d_in[3];
  const float* Wo = (const float*)d_in[4];
  const float* bo = (const float*)d_in[5];

  char* ws = (char*)d_ws;
  f16* wt   = (f16*)ws;                               // 8 MB
  f16* qkvh = (f16*)(ws + (size_t)8 * 1024 * 1024);   // 24 MB
  f16* ohp  = (f16*)(ws + (size_t)32 * 1024 * 1024);  // 8 MB (aliases xh)
  f16* vtb  = (f16*)(ws + (size_t)40 * 1024 * 1024);  // 8 MB
  f16* xh   = ohp;  // x-fp16 consumed by QKV GEMM before attn writes ohp

  k_prep<<<dim3(32, 32, 5), dim3(32, 8), 0, stream>>>(Wq, Wk, Wv, Wo, x, wt, xh);

  k_gemm5<<<768, 256, 0, stream>>>(xh, wt, qkvh);

  k_vtrans<<<dim3(32, 32), 256, 0, stream>>>(
      qkvh + (size_t)2 * MTOT * DIM, vtb);

  k_attn9<<<512, 512, 0, stream>>>(
      qkvh, qkvh + (size_t)MTOT * DIM, vtb, ohp);

  k_gemm3<<<dim3(32, 16), 256, 0, stream>>>(
      ohp, wt + (size_t)3 * DIM * DIM, (float*)d_out, bo);
}

// Round 16
// 113.944 us; speedup vs baseline: 1.0439x; 1.0439x over previous
//
#include <hip/hip_runtime.h>
#include <hip/hip_fp16.h>

typedef _Float16 f16;
typedef __attribute__((ext_vector_type(8))) _Float16 half8;
typedef __attribute__((ext_vector_type(2))) __fp16 fp16x2_native;
typedef __attribute__((ext_vector_type(4))) float floatx4;
typedef __attribute__((ext_vector_type(16))) float f32x16;
typedef __attribute__((ext_vector_type(4))) unsigned uint4v;
typedef __attribute__((ext_vector_type(2))) unsigned uint2v;

static constexpr int DIM = 1024;
static constexpr int SEQ = 2048;
static constexpr int DH = 64;
static constexpr int MTOT = 4096;  // BATCH * SEQ

__device__ __forceinline__ float fexp2(float x) {
#if __has_builtin(__builtin_amdgcn_exp2f)
  return __builtin_amdgcn_exp2f(x);
#else
  return exp2f(x);
#endif
}

__device__ __forceinline__ unsigned pkrtz(float a, float b) {
  fp16x2_native h = __builtin_amdgcn_cvt_pkrtz(a, b);
  return __builtin_bit_cast(unsigned, h);
}

__device__ __forceinline__ void pl32swap(unsigned& a, unsigned& b) {
#if __has_builtin(__builtin_amdgcn_permlane32_swap)
  uint2v r = __builtin_amdgcn_permlane32_swap(a, b, false, false);
  a = r.x;
  b = r.y;
#else
  asm volatile("v_permlane32_swap_b32 %0, %1" : "+v"(a), "+v"(b));
#endif
}

// async global->LDS 16B
__device__ __forceinline__ void gll16(const f16* g, f16* l) {
  auto gp = (__attribute__((address_space(1))) unsigned*)(uintptr_t)(const void*)g;
  auto lp = (__attribute__((address_space(3))) unsigned*)(uintptr_t)(void*)l;
  __builtin_amdgcn_global_load_lds(gp, lp, 16, 0, 0);
}

// ---- prep: z<4 = weight transpose+fp16 (wt[z][n][k]=W_z[k][n]); z==4 = x fp32->fp16 ----
__global__ __launch_bounds__(256) void k_prep(
    const float* __restrict__ Wq, const float* __restrict__ Wk,
    const float* __restrict__ Wv, const float* __restrict__ Wo,
    const float* __restrict__ x, f16* __restrict__ wt, f16* __restrict__ xh)
{
  const int z = blockIdx.z;
  const int tx = threadIdx.x, ty = threadIdx.y;
  if (z == 4) {
    const int i = (blockIdx.y * 32 + blockIdx.x) * 256 + ty * 32 + tx;  // 0..262143
    const float4* p = (const float4*)x + (size_t)i * 4;
    float4 v0 = p[0], v1 = p[1], v2 = p[2], v3 = p[3];
    half8 h0 = {(f16)v0.x, (f16)v0.y, (f16)v0.z, (f16)v0.w,
                (f16)v1.x, (f16)v1.y, (f16)v1.z, (f16)v1.w};
    half8 h1 = {(f16)v2.x, (f16)v2.y, (f16)v2.z, (f16)v2.w,
                (f16)v3.x, (f16)v3.y, (f16)v3.z, (f16)v3.w};
    *(half8*)(xh + (size_t)i * 16) = h0;
    *(half8*)(xh + (size_t)i * 16 + 8) = h1;
    return;
  }
  __shared__ float tile[32][33];
  const float* W = (z == 0) ? Wq : (z == 1) ? Wk : (z == 2) ? Wv : Wo;
  f16* out = wt + (size_t)z * DIM * DIM;
  const int x0 = blockIdx.x * 32, y0 = blockIdx.y * 32;
#pragma unroll
  for (int i = 0; i < 4; ++i)
    tile[ty + i * 8][tx] = W[(size_t)(y0 + ty + i * 8) * DIM + (x0 + tx)];
  __syncthreads();
#pragma unroll
  for (int i = 0; i < 4; ++i)
    out[(size_t)(x0 + ty + i * 8) * DIM + (y0 + tx)] = (f16)tile[tx][ty + i * 8];
}

// ---- V^T pre-transpose: vt[bh][d][n] = V[b][n][h*64+d] ----
__global__ __launch_bounds__(256) void k_vtrans(
    const f16* __restrict__ vh, f16* __restrict__ vt)
{
  __shared__ f16 T[64][72];
  const int tid = threadIdx.x;
  const int nt = blockIdx.x, bh = blockIdx.y;
  const int b = bh >> 4, h = bh & 15;
  const int n0 = nt * 64;
  const f16* src = vh + (size_t)b * SEQ * DIM + (size_t)h * DH;
#pragma unroll
  for (int i = 0; i < 2; ++i) {
    const int n = (tid >> 3) + i * 32;
    const int cc = tid & 7;
    half8 v = *(const half8*)(src + (size_t)(n0 + n) * DIM + cc * 8);
#pragma unroll
    for (int j = 0; j < 8; ++j) T[cc * 8 + j][n] = v[j];
  }
  __syncthreads();
  f16* dst = vt + (size_t)bh * DH * SEQ;
#pragma unroll
  for (int i = 0; i < 2; ++i) {
    const int d = (tid >> 3) + i * 32;
    const int cc = tid & 7;
    half8 w = *(const half8*)&T[d][cc * 8];
    *(half8*)(dst + (size_t)d * SEQ + n0 + cc * 8) = w;
  }
}

// ---- QKV GEMM: 256x256 tile, BK=32, 4 LDS buffers, depth-2 prefetch,
//      counted vmcnt(4), 1 barrier/K-tile (r13/r14 proven best) ----
__global__ __launch_bounds__(512, 1) void k_gemm4(
    const f16* __restrict__ A, const f16* __restrict__ BT, f16* __restrict__ C)
{
  __shared__ f16 SB[4][16384];  // per buf: A [256][32] at 0, B [256][32] at 8192

  const int tid = threadIdx.x;   // 0..511
  const int lane = tid & 63;
  const int wid = tid >> 6;      // 0..7
  const int wm = wid >> 2;       // 0..1 (M half)
  const int wn = wid & 3;        // 0..3 (N quarter)
  const int li = lane & 15, lg = lane >> 4;

  const int id = blockIdx.x;
  const int wg = (id & 7) * 24 + (id >> 3);
  const int bx = wg & 15;        // M tile 0..15
  const int by = wg >> 4;        // N tile 0..11
  const int row0 = bx * 256;
  const int col0 = by * 256;

  const int g0 = tid, g1 = tid + 512;
  const int r0 = g0 >> 2, sw0 = ((g0 & 3) ^ ((g0 >> 3) & 3)) * 8;
  const int r1 = g1 >> 2, sw1 = ((g1 & 3) ^ ((g1 >> 3) & 3)) * 8;
  const f16* pa0 = A + (size_t)(row0 + r0) * DIM + sw0;
  const f16* pa1 = A + (size_t)(row0 + r1) * DIM + sw1;
  const f16* pb0 = BT + (size_t)(col0 + r0) * DIM + sw0;
  const f16* pb1 = BT + (size_t)(col0 + r1) * DIM + sw1;

  auto issue = [&](int d) {
    f16* base = &SB[d][wid * 512];
    gll16(pa0, base);
    gll16(pa1, base + 4096);
    gll16(pb0, base + 8192);
    gll16(pb1, base + 12288);
    pa0 += 32; pa1 += 32; pb0 += 32; pb1 += 32;
  };

  const floatx4 zero4 = {0.f, 0.f, 0.f, 0.f};
  floatx4 acc[8][4];
#pragma unroll
  for (int f = 0; f < 8; ++f)
#pragma unroll
    for (int nf = 0; nf < 4; ++nf) acc[f][nf] = zero4;

  issue(0);
  issue(1);

  auto step = [&](int d, int t) {
    if (t < 31)
      asm volatile("s_waitcnt vmcnt(4)" ::: "memory");
    else
      asm volatile("s_waitcnt vmcnt(0)" ::: "memory");
    __builtin_amdgcn_s_barrier();
    if (t + 2 < 32) issue((d + 2) & 3);

    const f16* As = &SB[d][0];
    const f16* Bs = &SB[d][8192];
    half8 af[4], bf[4];
#pragma unroll
    for (int nf = 0; nf < 4; ++nf) {
      const int rb = wn * 64 + nf * 16 + li;
      bf[nf] = *(const half8*)&Bs[rb * 32 + (lg ^ ((rb >> 1) & 3)) * 8];
    }
#pragma unroll
    for (int f = 0; f < 4; ++f) {
      const int ra = wm * 128 + f * 16 + li;
      af[f] = *(const half8*)&As[ra * 32 + (lg ^ ((ra >> 1) & 3)) * 8];
    }
    __builtin_amdgcn_s_setprio(1);
#pragma unroll
    for (int f = 0; f < 4; ++f)
#pragma unroll
      for (int nf = 0; nf < 4; ++nf)
        acc[f][nf] = __builtin_amdgcn_mfma_f32_16x16x32_f16(af[f], bf[nf], acc[f][nf], 0, 0, 0);
    __builtin_amdgcn_s_setprio(0);
#pragma unroll
    for (int f = 0; f < 4; ++f) {
      const int ra = wm * 128 + 64 + f * 16 + li;
      af[f] = *(const half8*)&As[ra * 32 + (lg ^ ((ra >> 1) & 3)) * 8];
    }
    __builtin_amdgcn_s_setprio(1);
#pragma unroll
    for (int f = 0; f < 4; ++f)
#pragma unroll
      for (int nf = 0; nf < 4; ++nf)
        acc[4 + f][nf] = __builtin_amdgcn_mfma_f32_16x16x32_f16(af[f], bf[nf], acc[4 + f][nf], 0, 0, 0);
    __builtin_amdgcn_s_setprio(0);
  };

  for (int tt = 0; tt < 32; tt += 4) {
    step(0, tt);
    step(1, tt + 1);
    step(2, tt + 2);
    step(3, tt + 3);
  }

#pragma unroll
  for (int f = 0; f < 8; ++f)
#pragma unroll
    for (int nf = 0; nf < 4; ++nf) {
      const int colg = col0 + wn * 64 + nf * 16 + li;
      f16* Cz = C + (size_t)(colg >> 10) * ((size_t)MTOT * DIM) + (colg & 1023);
      const int rbase = row0 + wm * 128 + (f >> 2) * 64 + (f & 3) * 16 + lg * 4;
#pragma unroll
      for (int r = 0; r < 4; ++r)
        Cz[(size_t)(rbase + r) * DIM] = (f16)acc[f][nf][r];
    }
}

// ---- out-proj GEMM: 128x64 tile, 2-buffer, vmcnt(0) (r11 proven) ----
__global__ __launch_bounds__(256) void k_gemm3(
    const f16* __restrict__ A, const f16* __restrict__ BT,
    float* __restrict__ C, const float* __restrict__ bias)
{
  __shared__ f16 SB[2][6144];  // A 4096 f16 | B 2048 f16

  const int tid = threadIdx.x;
  const int lane = tid & 63;
  const int wid = tid >> 6;
  const int wr = (wid >> 1) * 64, wc = (wid & 1) * 32;
  const int li = lane & 15, lg = lane >> 4;

  const int row0 = blockIdx.x * 128, col0 = blockIdx.y * 64;

  const int c0 = tid, c1 = tid + 256;
  const f16* a0 = A + (size_t)(row0 + (c0 >> 2)) * DIM + (c0 & 3) * 8;
  const f16* a1 = A + (size_t)(row0 + (c1 >> 2)) * DIM + (c1 & 3) * 8;
  const f16* b0 = BT + (size_t)(col0 + (tid >> 2)) * DIM + (tid & 3) * 8;

  const floatx4 zero4 = {0.f, 0.f, 0.f, 0.f};
  floatx4 acc[4][2];
#pragma unroll
  for (int m = 0; m < 4; ++m)
#pragma unroll
    for (int n = 0; n < 2; ++n) acc[m][n] = zero4;

  auto issue = [&](int buf) {
    f16* B = &SB[buf][0];
    gll16(a0, B + tid * 8);
    gll16(a1, B + 2048 + tid * 8);
    gll16(b0, B + 4096 + tid * 8);
    a0 += 32; a1 += 32; b0 += 32;
  };

  issue(0);

  auto step = [&](int buf, int t) {
    asm volatile("s_waitcnt vmcnt(0)" ::: "memory");
    __builtin_amdgcn_s_barrier();
    asm volatile("" ::: "memory");
    if (t + 1 < 32) issue(buf ^ 1);
    const f16* As = &SB[buf][0];
    const f16* Bs = &SB[buf][4096];
    half8 af[4], bf[2];
#pragma unroll
    for (int m = 0; m < 4; ++m)
      af[m] = *(const half8*)&As[(wr + m * 16 + li) * 32 + lg * 8];
#pragma unroll
    for (int n = 0; n < 2; ++n)
      bf[n] = *(const half8*)&Bs[(wc + n * 16 + li) * 32 + lg * 8];
#pragma unroll
    for (int m = 0; m < 4; ++m)
#pragma unroll
      for (int n = 0; n < 2; ++n)
        acc[m][n] = __builtin_amdgcn_mfma_f32_16x16x32_f16(af[m], bf[n], acc[m][n], 0, 0, 0);
  };

  for (int t2 = 0; t2 < 32; t2 += 2) {
    step(0, t2);
    step(1, t2 + 1);
  }

#pragma unroll
  for (int m = 0; m < 4; ++m)
#pragma unroll
    for (int n = 0; n < 2; ++n)
#pragma unroll
      for (int r = 0; r < 4; ++r) {
        const int row = row0 + wr + m * 16 + lg * 4 + r;
        const int col = col0 + wc + n * 16 + li;
        C[(size_t)row * DIM + col] = acc[m][n][r] + bias[col];
      }
}

// ---- flash attention v9 (r14 proven, unchanged) ----
__global__ __launch_bounds__(512) void k_attn9(
    const f16* __restrict__ qh, const f16* __restrict__ kh,
    const f16* __restrict__ vt, f16* __restrict__ oh)
{
  __shared__ f16 KV[2][16384];   // [buf][K0|V0|K1|V1] 4096 f16 each, 16B-col swizzled
  __shared__ float bc[8][32];
  __shared__ float Lm[4][32], Ll[4][32], W0[4][32], W1[4][32];

  const int tid = threadIdx.x;
  const int lane = tid & 63;
  const int wid = tid >> 6;   // 0..7
  const int g = wid >> 2;     // kv-half group
  const int sub = wid & 3;    // q-subtile
  const int col = lane & 31;
  const int hi = lane >> 5;

  const int id = blockIdx.x;
  const int xcd = id & 7;
  const int j = id >> 3;
  const int bh = xcd * 4 + (j >> 4);
  const int qi = j & 15;
  const int b = bh >> 4, h = bh & 15;

  const int q0 = qi * 128 + sub * 32;
  const size_t xbase = (size_t)b * SEQ * DIM + (size_t)h * DH;
  const size_t vtbase = (size_t)bh * DH * SEQ;

  const float SC = 0.125f * 1.44269504089f;  // scale * log2(e)
  const float RTRAW = 8.0f / SC;

  const int lc = tid & 511;
  const int srow = lc >> 3;
  const int sw = ((lc & 7) ^ (srow & 7)) * 8;
  const f16* ks0 = kh + xbase + (size_t)srow * DIM + sw;
  const f16* ks1 = kh + xbase + (size_t)(1024 + srow) * DIM + sw;
  const f16* vs0 = vt + vtbase + (size_t)srow * SEQ + sw;
  const f16* vs1 = vt + vtbase + (size_t)srow * SEQ + 1024 + sw;

  auto issue = [&](int buf) {
    f16* B = &KV[buf][wid * 512];
    gll16(ks0, B);
    gll16(vs0, B + 4096);
    gll16(ks1, B + 8192);
    gll16(vs1, B + 12288);
    ks0 += 64 * DIM; ks1 += 64 * DIM; vs0 += 64; vs1 += 64;
  };

  half8 qb[4];
  {
    const f16* qrow = qh + xbase + (size_t)(q0 + col) * DIM;
#pragma unroll
    for (int s = 0; s < 4; ++s) qb[s] = *(const half8*)(qrow + s * 16 + hi * 8);
  }

  f32x16 o0 = {0, 0, 0, 0, 0, 0, 0, 0, 0, 0, 0, 0, 0, 0, 0, 0};
  f32x16 o1 = {0, 0, 0, 0, 0, 0, 0, 0, 0, 0, 0, 0, 0, 0, 0, 0};
  float m = -1e30f, mc = -1e30f;  // mc = m*SC kept in sync
  float lsum = 0.f;               // per-lane half-row partial

  issue(0);

  auto tile = [&](int buf, int t) {
    asm volatile("s_waitcnt vmcnt(0)" ::: "memory");
    __builtin_amdgcn_s_barrier();
    asm volatile("" ::: "memory");
    if (t < 15) issue(buf ^ 1);
    const f16* Ks = &KV[buf][g * 8192];
    const f16* Vs = Ks + 4096;

#pragma unroll
    for (int kvs = 0; kvs < 2; ++kvs) {
      const int krow = kvs * 32 + col;
      f32x16 sacc = {0, 0, 0, 0, 0, 0, 0, 0, 0, 0, 0, 0, 0, 0, 0, 0};
      __builtin_amdgcn_s_setprio(1);
#pragma unroll
      for (int s = 0; s < 4; ++s) {
        const int cc = (2 * s + hi) ^ (krow & 7);
        half8 ka = *(const half8*)&Ks[krow * 64 + cc * 8];
        sacc = __builtin_amdgcn_mfma_f32_32x32x16_f16(ka, qb[s], sacc, 0, 0, 0);
      }
      __builtin_amdgcn_s_setprio(0);

      // speculative exp2 with current m (off the max-tree path)
      float pw[16];
#pragma unroll
      for (int r = 0; r < 16; ++r) pw[r] = fexp2(fmaf(sacc[r], SC, -mc));

      float x0 = fmaxf(fmaxf(sacc[0], sacc[1]), fmaxf(sacc[2], sacc[3]));
      float x1 = fmaxf(fmaxf(sacc[4], sacc[5]), fmaxf(sacc[6], sacc[7]));
      float x2 = fmaxf(fmaxf(sacc[8], sacc[9]), fmaxf(sacc[10], sacc[11]));
      float x3 = fmaxf(fmaxf(sacc[12], sacc[13]), fmaxf(sacc[14], sacc[15]));
      const float smax = fmaxf(fmaxf(x0, x1), fmaxf(x2, x3));

      if (!__all(smax <= m + RTRAW)) {  // rare: first tile + outliers
        const float psm = fmaxf(smax, __shfl_xor(smax, 32));  // pair-consistent
        const float mn = fmaxf(m, psm);
        const float alpha = fexp2((m - mn) * SC);
        m = mn;
        mc = m * SC;
        lsum *= alpha;
        if (hi == 0) bc[wid][col] = alpha;
#pragma unroll
        for (int r = 0; r < 16; ++r) {
          const float a2 = bc[wid][(r & 3) + 8 * (r >> 2) + 4 * hi];
          o0[r] *= a2;
          o1[r] *= a2;
        }
#pragma unroll
        for (int r = 0; r < 16; ++r) pw[r] = fexp2(fmaf(sacc[r], SC, -mc));
      }

      float s0 = (pw[0] + pw[1]) + (pw[2] + pw[3]);
      float s1 = (pw[4] + pw[5]) + (pw[6] + pw[7]);
      float s2 = (pw[8] + pw[9]) + (pw[10] + pw[11]);
      float s3 = (pw[12] + pw[13]) + (pw[14] + pw[15]);
      lsum += (s0 + s1) + (s2 + s3);  // deferred combine

      __builtin_amdgcn_s_setprio(1);
#pragma unroll
      for (int s2i = 0; s2i < 2; ++s2i) {
        const int rb = s2i * 8;
        unsigned X0 = pkrtz(pw[rb + 0], pw[rb + 1]);
        unsigned X1 = pkrtz(pw[rb + 2], pw[rb + 3]);
        unsigned Y0 = pkrtz(pw[rb + 4], pw[rb + 5]);
        unsigned Y1 = pkrtz(pw[rb + 6], pw[rb + 7]);
        pl32swap(X0, Y0);
        pl32swap(X1, Y1);
        const half8 paf = __builtin_bit_cast(half8, (uint4v){X0, X1, Y0, Y1});
        const int kc = kvs * 4 + s2i * 2 + hi;
#pragma unroll
        for (int dt = 0; dt < 2; ++dt) {
          const int vrow = dt * 32 + col;
          const int cc = kc ^ (vrow & 7);
          half8 vb = *(const half8*)&Vs[vrow * 64 + cc * 8];
          if (dt == 0)
            o0 = __builtin_amdgcn_mfma_f32_32x32x16_f16(paf, vb, o0, 0, 0, 0);
          else
            o1 = __builtin_amdgcn_mfma_f32_32x32x16_f16(paf, vb, o1, 0, 0, 0);
        }
      }
      __builtin_amdgcn_s_setprio(0);
    }
  };

  for (int t2 = 0; t2 < 16; t2 += 2) {
    tile(0, t2);
    tile(1, t2 + 1);
  }

  lsum += __shfl_xor(lsum, 32);  // full row-sum for q = col

  if (g == 1) {
    const float inv = 1.0f / lsum;
    if (hi == 0) { Lm[sub][col] = m; Ll[sub][col] = lsum; bc[wid][col] = inv; }
    f16* po = &KV[0][0] + sub * 2048;
#pragma unroll
    for (int r = 0; r < 16; ++r) {
      const int qr = (r & 3) + 8 * (r >> 2) + 4 * hi;
      const float iv = bc[wid][qr];
      po[qr * 64 + col] = (f16)(o0[r] * iv);
      po[qr * 64 + 32 + col] = (f16)(o1[r] * iv);
    }
  }
  __syncthreads();
  if (g == 0) {
    const float m1 = Lm[sub][col], l1 = Ll[sub][col];
    const float M = fmaxf(m, m1);
    const float e0 = fexp2((m - M) * SC);
    const float a0 = lsum * e0;
    const float a1 = l1 * fexp2((m1 - M) * SC);
    const float rden = 1.0f / (a0 + a1);
    const float c0 = e0 * rden;
    const float w1 = a1 * rden;
    if (hi == 0) { W0[sub][col] = c0; W1[sub][col] = w1; }
    const f16* po = &KV[0][0] + sub * 2048;
#pragma unroll
    for (int r = 0; r < 16; ++r) {
      const int qr = (r & 3) + 8 * (r >> 2) + 4 * hi;
      const float c0r = W0[sub][qr], w1r = W1[sub][qr];
      f16* orow = oh + xbase + (size_t)(q0 + qr) * DIM;
      orow[col] = (f16)(c0r * o0[r] + w1r * (float)po[qr * 64 + col]);
      orow[32 + col] = (f16)(c0r * o1[r] + w1r * (float)po[qr * 64 + 32 + col]);
    }
  }
}

extern "C" void kernel_launch(void* const* d_in, const int* in_sizes, int n_in,
                              void* d_out, int out_size, void* d_ws, size_t ws_size,
                              hipStream_t stream)
{
  const float* x  = (const float*)d_in[0];
  const float* Wq = (const float*)d_in[1];
  const float* Wk = (const float*)d_in[2];
  const float* Wv = (const float*)d_in[3];
  const float* Wo = (const float*)d_in[4];
  const float* bo = (const float*)d_in[5];

  char* ws = (char*)d_ws;
  f16* wt   = (f16*)ws;                               // 8 MB
  f16* qkvh = (f16*)(ws + (size_t)8 * 1024 * 1024);   // 24 MB
  f16* ohp  = (f16*)(ws + (size_t)32 * 1024 * 1024);  // 8 MB (aliases xh)
  f16* vtb  = (f16*)(ws + (size_t)40 * 1024 * 1024);  // 8 MB
  f16* xh   = ohp;  // x-fp16 consumed by QKV GEMM before attn writes ohp

  k_prep<<<dim3(32, 32, 5), dim3(32, 8), 0, stream>>>(Wq, Wk, Wv, Wo, x, wt, xh);

  k_gemm4<<<192, 512, 0, stream>>>(xh, wt, qkvh);

  k_vtrans<<<dim3(32, 32), 256, 0, stream>>>(
      qkvh + (size_t)2 * MTOT * DIM, vtb);

  k_attn9<<<512, 512, 0, stream>>>(
      qkvh, qkvh + (size_t)MTOT * DIM, vtb, ohp);

  k_gemm3<<<dim3(32, 16), 256, 0, stream>>>(
      ohp, wt + (size_t)3 * DIM * DIM, (float*)d_out, bo);
}